// Round 5
// baseline (137.588 us; speedup 1.0000x reference)
//
#include <hip/hip_runtime.h>

#define N 8192
#define H 256
#define TOPK 16
#define NSEC 11
#define NEG_SLOPE 0.2
#define NB 256                 // K1 blocks (one per CU)
#define NT 256                 // threads per block
#define RPB (N / NB)           // 32 rows per block
#define NSL 8                  // slices per sector
#define SLICE (N / NSL)        // 1024 elements per slice
#define NWB 256                // K2 blocks (88 selection + all write)
#define IDX_SENT 0x7fffffff

// flag area: every counter/flag on its own 256-B line (64 ints)
#define FSTRIDE 64
#define ARR(c)  ((c) * FSTRIDE)            // 11 sector-arrival counters
#define DCNT    (NSEC * FSTRIDE)           // merged-sector count (never polled)
#define DREP(x) ((NSEC + 1 + (x)) * FSTRIDE)  // 8 replicated done flags
#define NFLAGS  ((NSEC + 1 + 8) * FSTRIDE)    // 1280 ints

__device__ __forceinline__ bool better(double av, int ai, double bv, int bi) {
    return (av > bv) || (av == bv && ai < bi);
}

// ---------------------------------------------------------------------------
// K1: redundant v = W^T a per block (4 independent f64 chains, proven),
// then s1/s2 for the block's 32 rows. Block 0 zeroes the (padded) flag area.
// ---------------------------------------------------------------------------
__global__ __launch_bounds__(NT) void compute_v_s(
    const float* __restrict__ E, const float* __restrict__ W,
    const float* __restrict__ a,
    float* __restrict__ s1f, double* __restrict__ s2g,
    int* __restrict__ flags)
{
    __shared__ float sa[2 * H];
    __shared__ double sv1[H];
    __shared__ double sv2[H];

    int t = threadIdx.x;
    int blk = blockIdx.x;
    int lane = t & 63;
    int w = t >> 6;  // wave 0..3

    if (blk == 0) {
        for (int z = t; z < NFLAGS; z += NT) flags[z] = 0;
    }

    sa[t] = a[t];
    sa[t + H] = a[t + H];
    __syncthreads();

    // ---- phase A: thread t owns column t; 4 independent chains ----
    {
        double a1_0 = 0.0, a1_1 = 0.0, a1_2 = 0.0, a1_3 = 0.0;
        double a2_0 = 0.0, a2_1 = 0.0, a2_2 = 0.0, a2_3 = 0.0;
        for (int j = 0; j < H; j += 4) {
            double w0 = (double)W[(j + 0) * H + t];
            double w1 = (double)W[(j + 1) * H + t];
            double w2 = (double)W[(j + 2) * H + t];
            double w3 = (double)W[(j + 3) * H + t];
            a1_0 += w0 * (double)sa[j + 0];
            a1_1 += w1 * (double)sa[j + 1];
            a1_2 += w2 * (double)sa[j + 2];
            a1_3 += w3 * (double)sa[j + 3];
            a2_0 += w0 * (double)sa[H + j + 0];
            a2_1 += w1 * (double)sa[H + j + 1];
            a2_2 += w2 * (double)sa[H + j + 2];
            a2_3 += w3 * (double)sa[H + j + 3];
        }
        sv1[t] = (a1_0 + a1_1) + (a1_2 + a1_3);
        sv2[t] = (a2_0 + a2_1) + (a2_2 + a2_3);
    }
    __syncthreads();

    // ---- phase B: rows [blk*32 .. +32), wave-per-row, loads batched ----
    {
        float4 e[RPB / 4];
#pragma unroll
        for (int q = 0; q < RPB / 4; ++q) {
            int row = blk * RPB + (w + 4 * q);
            e[q] = ((const float4*)(E + (size_t)row * H))[lane];
        }
        int base = lane * 4;
        double b10 = sv1[base + 0], b11 = sv1[base + 1],
               b12 = sv1[base + 2], b13 = sv1[base + 3];
        double b20 = sv2[base + 0], b21 = sv2[base + 1],
               b22 = sv2[base + 2], b23 = sv2[base + 3];
#pragma unroll
        for (int q = 0; q < RPB / 4; ++q) {
            int row = blk * RPB + (w + 4 * q);
            double acc1 = (double)e[q].x * b10 + (double)e[q].y * b11 +
                          (double)e[q].z * b12 + (double)e[q].w * b13;
            double acc2 = (double)e[q].x * b20 + (double)e[q].y * b21 +
                          (double)e[q].z * b22 + (double)e[q].w * b23;
            for (int o = 32; o > 0; o >>= 1) {
                acc1 += __shfl_down(acc1, o);
                acc2 += __shfl_down(acc2, o);
            }
            if (lane == 0) {
                s1f[row] = (float)acc1;
                s2g[row] = acc2;               // f64 ordering key
            }
        }
    }
}

// ---------------------------------------------------------------------------
// K2 (slice_merge_write): 256 blocks.
//  blocks 0..87: proven slice top-16 + last-block sector merge. Each merger
//    publishes, fences, bumps dcnt (NOT polled); the 11th merger broadcasts
//    into 8 replicated per-line done flags.
//  ALL blocks: write inactive-row outputs pre-wait (no merge dependency),
//    then poll replica (bx&7) with s_sleep backoff, fence, write active rows.
//  R4 lesson: arrive/done shared one cacheline polled by 256 blocks at agent
//  scope -> L2-bank congestion delayed the atomic chain ~40us. All flags now
//  line-isolated and poll traffic is spread 8-way at ~1us cadence.
// ---------------------------------------------------------------------------
__global__ __launch_bounds__(NT) void slice_merge_write(
    const float* __restrict__ s1f, const double* __restrict__ s2g,
    const int* __restrict__ sec, const int* __restrict__ act,
    double* __restrict__ candV, int* __restrict__ candI,
    int* __restrict__ cnts, int* __restrict__ flags,
    int* __restrict__ top_idx, int* __restrict__ fill_idx,
    int* __restrict__ m_arr, float* __restrict__ out)
{
    __shared__ double wV[4][TOPK];
    __shared__ int wI[4][TOPK];
    __shared__ int wCnt[4];
    __shared__ int sLast;

    int bx = blockIdx.x;
    int t = threadIdx.x;
    int lane = t & 63;
    int w = t >> 6;

    // ================= selection + sector merge (blocks 0..87) =============
    if (bx < NSEC * NSL) {
        int c = bx >> 3;       // sector 0..10
        int sl = bx & 7;       // slice 0..7

        int j0 = sl * SLICE + 4 * t;
        int4 a4 = *(const int4*)(act + j0);
        int4 s4 = *(const int4*)(sec + j0);
        double2 d01 = *(const double2*)(s2g + j0);
        double2 d23 = *(const double2*)(s2g + j0 + 2);

        bool p0 = (a4.x != 0) && (s4.x == c);
        bool p1 = (a4.y != 0) && (s4.y == c);
        bool p2 = (a4.z != 0) && (s4.z == c);
        bool p3 = (a4.w != 0) && (s4.w == c);

        double v[4];
        int ix[4];
        v[0] = p0 ? d01.x : -INFINITY;  ix[0] = p0 ? (j0 + 0) : IDX_SENT;
        v[1] = p1 ? d01.y : -INFINITY;  ix[1] = p1 ? (j0 + 1) : IDX_SENT;
        v[2] = p2 ? d23.x : -INFINITY;  ix[2] = p2 ? (j0 + 2) : IDX_SENT;
        v[3] = p3 ? d23.y : -INFINITY;  ix[3] = p3 ? (j0 + 3) : IDX_SENT;

        int cnt = __popcll(__ballot(p0)) + __popcll(__ballot(p1)) +
                  __popcll(__ballot(p2)) + __popcll(__ballot(p3));

        // per-wave 16-round selection (proven)
        for (int r = 0; r < TOPK; ++r) {
            double bv = v[0];
            int bi = ix[0];
#pragma unroll
            for (int p = 1; p < 4; ++p)
                if (better(v[p], ix[p], bv, bi)) { bv = v[p]; bi = ix[p]; }
            for (int o = 32; o > 0; o >>= 1) {
                double ov = __shfl_xor(bv, o);
                int oi = __shfl_xor(bi, o);
                if (better(ov, oi, bv, bi)) { bv = ov; bi = oi; }
            }
#pragma unroll
            for (int p = 0; p < 4; ++p)
                if (ix[p] == bi) { v[p] = -INFINITY; ix[p] = IDX_SENT; }
            if (lane == 0) {
                wV[w][r] = bv;
                wI[w][r] = bi;
            }
        }
        if (lane == 0) wCnt[w] = cnt;
        __syncthreads();

        // block merge (proven) + arrival on line-isolated counter
        if (w == 0) {
            double mv = wV[lane >> 4][lane & 15];
            int mi = wI[lane >> 4][lane & 15];
            for (int r = 0; r < TOPK; ++r) {
                double bv = mv;
                int bi = mi;
                for (int o = 32; o > 0; o >>= 1) {
                    double ov = __shfl_xor(bv, o);
                    int oi = __shfl_xor(bi, o);
                    if (better(ov, oi, bv, bi)) { bv = ov; bi = oi; }
                }
                if (mi == bi) { mv = -INFINITY; mi = IDX_SENT; }
                if (lane == 0) {
                    candV[bx * TOPK + r] = bv;
                    candI[bx * TOPK + r] = bi;
                }
            }
            if (lane == 0) {
                cnts[bx] = wCnt[0] + wCnt[1] + wCnt[2] + wCnt[3];
                __threadfence();                        // release candV/candI/cnts
                int old = atomicAdd(&flags[ARR(c)], 1); // device-scope
                sLast = (old == NSL - 1);
            }
        }
        __syncthreads();

        if (sLast) {
            // ---- merger tail (proven): last block of this sector ----
            __threadfence();   // acquire other slices' candV/candI/cnts

            if (w == 0) {
                const double* cbV = candV + (size_t)c * NSL * TOPK;
                const int* cbI = candI + (size_t)c * NSL * TOPK;
                double v0 = cbV[lane];
                int i0 = cbI[lane];
                double v1 = cbV[lane + 64];
                int i1 = cbI[lane + 64];
                for (int r = 0; r < TOPK; ++r) {
                    double bv;
                    int bi;
                    if (better(v0, i0, v1, i1)) { bv = v0; bi = i0; }
                    else                        { bv = v1; bi = i1; }
                    for (int o = 32; o > 0; o >>= 1) {
                        double ov = __shfl_xor(bv, o);
                        int oi = __shfl_xor(bi, o);
                        if (better(ov, oi, bv, bi)) { bv = ov; bi = oi; }
                    }
                    if (i0 == bi)      { v0 = -INFINITY; i0 = IDX_SENT; }
                    else if (i1 == bi) { v1 = -INFINITY; i1 = IDX_SENT; }
                    if (lane == 0) top_idx[c * TOPK + r] = (bi == IDX_SENT) ? -1 : bi;
                }
                // m = min(16, total active in sector)
                int cl = (lane < NSL) ? cnts[c * NSL + lane] : 0;
                for (int o = 32; o > 0; o >>= 1) cl += __shfl_xor(cl, o);
                if (lane == 0) m_arr[c] = (cl < TOPK) ? cl : TOPK;
            } else if (w == 1) {
                // fill indices: first 16 j failing the predicate
                int cnt2 = 0;
                for (int basej = 0; basej < N && cnt2 < TOPK; basej += 64) {
                    int j = basej + lane;
                    bool fail = !((act[j] != 0) && (sec[j] == c));
                    unsigned long long mask = __ballot(fail);
                    if (fail) {
                        int rank = cnt2 + __popcll(mask & ((1ull << lane) - 1));
                        if (rank < TOPK) fill_idx[c * TOPK + rank] = j;
                    }
                    cnt2 += __popcll(mask);
                }
            }
            __syncthreads();                 // both waves' stores done
            if (t == 0) {
                __threadfence();             // release top_idx/fill_idx/m_arr
                int od = atomicAdd(&flags[DCNT], 1);   // nobody polls this line
                if (od == NSEC - 1) {
                    // last sector merged: broadcast into 8 per-line replicas
#pragma unroll
                    for (int x = 0; x < 8; ++x)
                        __hip_atomic_store(&flags[DREP(x)], 1,
                                           __ATOMIC_RELEASE,
                                           __HIP_MEMORY_SCOPE_AGENT);
                }
            }
        }
    }

    // ================= writer: 2 gids per thread =================
    int g0 = bx * (2 * NT) + t;
    int g1 = g0 + NT;
    int i0w = g0 >> 4, i1w = g1 >> 4;
    int a0w = act[i0w], a1w = act[i1w];
    int se0 = sec[i0w], se1 = sec[i1w];

    // pre-wait: inactive rows need no merge data
    if (a0w == 0) {
        out[g0] = 0.0f;
        out[N * TOPK + g0] = (float)(g0 & 15);
        out[2 * N * TOPK + g0] = 0.0f;
    }
    if (a1w == 0) {
        out[g1] = 0.0f;
        out[N * TOPK + g1] = (float)(g1 & 15);
        out[2 * N * TOPK + g1] = 0.0f;
    }

    // one-shot flag wait, poll traffic spread across 8 isolated lines
    if (t == 0) {
        while (__hip_atomic_load(&flags[DREP(bx & 7)], __ATOMIC_RELAXED,
                                 __HIP_MEMORY_SCOPE_AGENT) == 0) {
            __builtin_amdgcn_s_sleep(32);
        }
    }
    __syncthreads();
    __threadfence();   // acquire: top_idx/fill_idx/m_arr from merger blocks

    // active rows (proven round-0 math)
    if (a0w != 0) {
        int c = se0, m = m_arr[c], slot = g0 & 15;
        float wgt = 0.0f, fvalid = 0.0f, fidx;
        if (slot < m) {
            int j = top_idx[c * TOPK + slot];
            double x = (double)s1f[i0w] + s2g[j];
            double attv = (x >= 0.0) ? x : NEG_SLOPE * x;
            wgt = (float)attv;
            fvalid = 1.0f;
            fidx = (float)j;
        } else {
            fidx = (float)fill_idx[c * TOPK + (slot - m)];
        }
        out[g0] = wgt;
        out[N * TOPK + g0] = fidx;
        out[2 * N * TOPK + g0] = fvalid;
    }
    if (a1w != 0) {
        int c = se1, m = m_arr[c], slot = g1 & 15;
        float wgt = 0.0f, fvalid = 0.0f, fidx;
        if (slot < m) {
            int j = top_idx[c * TOPK + slot];
            double x = (double)s1f[i1w] + s2g[j];
            double attv = (x >= 0.0) ? x : NEG_SLOPE * x;
            wgt = (float)attv;
            fvalid = 1.0f;
            fidx = (float)j;
        } else {
            fidx = (float)fill_idx[c * TOPK + (slot - m)];
        }
        out[g1] = wgt;
        out[N * TOPK + g1] = fidx;
        out[2 * N * TOPK + g1] = fvalid;
    }
}

extern "C" void kernel_launch(void* const* d_in, const int* in_sizes, int n_in,
                              void* d_out, int out_size, void* d_ws, size_t ws_size,
                              hipStream_t stream) {
    const float* E = (const float*)d_in[0];
    const float* W = (const float*)d_in[1];
    const float* a = (const float*)d_in[2];
    const int* sec = (const int*)d_in[3];
    const int* act = (const int*)d_in[4];  // bool input uploaded as int32

    // workspace (~121 KB, 8-byte aligned first)
    char* ws = (char*)d_ws;
    double* s2g = (double*)ws;                             // N f64
    double* candV = s2g + N;                               // NSEC*NSL*TOPK f64
    float* s1f = (float*)(candV + NSEC * NSL * TOPK);      // N f32
    int* candI = (int*)(s1f + N);                          // NSEC*NSL*TOPK i32
    int* cnts = candI + NSEC * NSL * TOPK;                 // NSEC*NSL = 88
    int* top_idx = cnts + NSEC * NSL;                      // NSEC*TOPK
    int* fill_idx = top_idx + NSEC * TOPK;                 // NSEC*TOPK
    int* m_arr = fill_idx + NSEC * TOPK;                   // NSEC
    // line-isolated flag area, 256-B aligned
    int* flags = (int*)((((size_t)(m_arr + NSEC)) + 255) & ~(size_t)255);

    float* out = (float*)d_out;

    hipLaunchKernelGGL(compute_v_s, dim3(NB), dim3(NT), 0, stream,
                       E, W, a, s1f, s2g, flags);
    hipLaunchKernelGGL(slice_merge_write, dim3(NWB), dim3(NT), 0, stream,
                       s1f, s2g, sec, act, candV, candI, cnts, flags,
                       top_idx, fill_idx, m_arr, out);
}

// Round 6
// 110.879 us; speedup vs baseline: 1.2409x; 1.2409x over previous
//
#include <hip/hip_runtime.h>

#define N 8192
#define H 256
#define TOPK 16
#define NSEC 11
#define NEG_SLOPE 0.2
#define NB 256                 // K1 blocks (one per CU)
#define NT 256                 // threads per block
#define RPB (N / NB)           // 32 rows per block
#define NSL 8                  // slices per sector in slice_topk
#define SLICE (N / NSL)        // 1024 elements per slice
#define IDX_SENT 0x7fffffff

__device__ __forceinline__ bool better(double av, int ai, double bv, int bi) {
    return (av > bv) || (av == bv && ai < bi);
}

// ---------------------------------------------------------------------------
// K1: redundant v = W^T a per block (4 independent f64 chains, proven),
// then s1/s2 for the block's 32 rows. Phase B issues all 8 row-loads per
// wave up front and hoists sv1/sv2 LDS reads to registers. Proven R0 best.
// ---------------------------------------------------------------------------
__global__ __launch_bounds__(NT) void compute_v_s(
    const float* __restrict__ E, const float* __restrict__ W,
    const float* __restrict__ a,
    float* __restrict__ s1f, double* __restrict__ s2g)
{
    __shared__ float sa[2 * H];
    __shared__ double sv1[H];
    __shared__ double sv2[H];

    int t = threadIdx.x;
    int blk = blockIdx.x;
    int lane = t & 63;
    int w = t >> 6;  // wave 0..3

    sa[t] = a[t];
    sa[t + H] = a[t + H];
    __syncthreads();

    // ---- phase A: thread t owns column t; 4 independent chains ----
    {
        double a1_0 = 0.0, a1_1 = 0.0, a1_2 = 0.0, a1_3 = 0.0;
        double a2_0 = 0.0, a2_1 = 0.0, a2_2 = 0.0, a2_3 = 0.0;
        for (int j = 0; j < H; j += 4) {
            double w0 = (double)W[(j + 0) * H + t];
            double w1 = (double)W[(j + 1) * H + t];
            double w2 = (double)W[(j + 2) * H + t];
            double w3 = (double)W[(j + 3) * H + t];
            a1_0 += w0 * (double)sa[j + 0];
            a1_1 += w1 * (double)sa[j + 1];
            a1_2 += w2 * (double)sa[j + 2];
            a1_3 += w3 * (double)sa[j + 3];
            a2_0 += w0 * (double)sa[H + j + 0];
            a2_1 += w1 * (double)sa[H + j + 1];
            a2_2 += w2 * (double)sa[H + j + 2];
            a2_3 += w3 * (double)sa[H + j + 3];
        }
        sv1[t] = (a1_0 + a1_1) + (a1_2 + a1_3);
        sv2[t] = (a2_0 + a2_1) + (a2_2 + a2_3);
    }
    __syncthreads();

    // ---- phase B: rows [blk*32 .. +32), wave-per-row, loads batched ----
    {
        float4 e[RPB / 4];                       // 8 row fragments, independent
#pragma unroll
        for (int q = 0; q < RPB / 4; ++q) {
            int row = blk * RPB + (w + 4 * q);
            e[q] = ((const float4*)(E + (size_t)row * H))[lane];
        }
        int base = lane * 4;
        double b10 = sv1[base + 0], b11 = sv1[base + 1],
               b12 = sv1[base + 2], b13 = sv1[base + 3];
        double b20 = sv2[base + 0], b21 = sv2[base + 1],
               b22 = sv2[base + 2], b23 = sv2[base + 3];
#pragma unroll
        for (int q = 0; q < RPB / 4; ++q) {
            int row = blk * RPB + (w + 4 * q);
            double acc1 = (double)e[q].x * b10 + (double)e[q].y * b11 +
                          (double)e[q].z * b12 + (double)e[q].w * b13;
            double acc2 = (double)e[q].x * b20 + (double)e[q].y * b21 +
                          (double)e[q].z * b22 + (double)e[q].w * b23;
            for (int o = 32; o > 0; o >>= 1) {
                acc1 += __shfl_down(acc1, o);
                acc2 += __shfl_down(acc2, o);
            }
            if (lane == 0) {
                s1f[row] = (float)acc1;
                s2g[row] = acc2;               // f64 ordering key
            }
        }
    }
}

// ---------------------------------------------------------------------------
// K2: 88 blocks = 11 sectors x 8 slices of 1024. Hierarchical selection with
// max 4 candidates per lane (no scratch spill). Proven, unchanged.
// ---------------------------------------------------------------------------
__global__ __launch_bounds__(NT) void slice_topk(
    const double* __restrict__ s2g, const int* __restrict__ sec,
    const int* __restrict__ act,
    double* __restrict__ candV, int* __restrict__ candI,
    int* __restrict__ cnts)
{
    __shared__ double wV[4][TOPK];
    __shared__ int wI[4][TOPK];
    __shared__ int wCnt[4];

    int bx = blockIdx.x;
    int c = bx >> 3;       // sector 0..10
    int sl = bx & 7;       // slice 0..7
    int t = threadIdx.x;
    int lane = t & 63;
    int w = t >> 6;

    int j0 = sl * SLICE + 4 * t;
    int4 a4 = *(const int4*)(act + j0);
    int4 s4 = *(const int4*)(sec + j0);
    double2 d01 = *(const double2*)(s2g + j0);
    double2 d23 = *(const double2*)(s2g + j0 + 2);

    bool p0 = (a4.x != 0) && (s4.x == c);
    bool p1 = (a4.y != 0) && (s4.y == c);
    bool p2 = (a4.z != 0) && (s4.z == c);
    bool p3 = (a4.w != 0) && (s4.w == c);

    double v[4];
    int ix[4];
    v[0] = p0 ? d01.x : -INFINITY;  ix[0] = p0 ? (j0 + 0) : IDX_SENT;
    v[1] = p1 ? d01.y : -INFINITY;  ix[1] = p1 ? (j0 + 1) : IDX_SENT;
    v[2] = p2 ? d23.x : -INFINITY;  ix[2] = p2 ? (j0 + 2) : IDX_SENT;
    v[3] = p3 ? d23.y : -INFINITY;  ix[3] = p3 ? (j0 + 3) : IDX_SENT;

    int cnt = __popcll(__ballot(p0)) + __popcll(__ballot(p1)) +
              __popcll(__ballot(p2)) + __popcll(__ballot(p3));

    for (int r = 0; r < TOPK; ++r) {
        double bv = v[0];
        int bi = ix[0];
#pragma unroll
        for (int p = 1; p < 4; ++p)
            if (better(v[p], ix[p], bv, bi)) { bv = v[p]; bi = ix[p]; }
        for (int o = 32; o > 0; o >>= 1) {
            double ov = __shfl_xor(bv, o);
            int oi = __shfl_xor(bi, o);
            if (better(ov, oi, bv, bi)) { bv = ov; bi = oi; }
        }
#pragma unroll
        for (int p = 0; p < 4; ++p)
            if (ix[p] == bi) { v[p] = -INFINITY; ix[p] = IDX_SENT; }
        if (lane == 0) {
            wV[w][r] = bv;
            wI[w][r] = bi;
        }
    }
    if (lane == 0) wCnt[w] = cnt;
    __syncthreads();

    if (w == 0) {
        double mv = wV[lane >> 4][lane & 15];
        int mi = wI[lane >> 4][lane & 15];
        for (int r = 0; r < TOPK; ++r) {
            double bv = mv;
            int bi = mi;
            for (int o = 32; o > 0; o >>= 1) {
                double ov = __shfl_xor(bv, o);
                int oi = __shfl_xor(bi, o);
                if (better(ov, oi, bv, bi)) { bv = ov; bi = oi; }
            }
            if (mi == bi) { mv = -INFINITY; mi = IDX_SENT; }
            if (lane == 0) {
                candV[bx * TOPK + r] = bv;
                candI[bx * TOPK + r] = bi;
            }
        }
        if (lane == 0) cnts[bx] = wCnt[0] + wCnt[1] + wCnt[2] + wCnt[3];
    }
}

// ---------------------------------------------------------------------------
// K3: one wave per sector. Merge 8 sorted 16-lists (= 128 candidates, 2 per
// lane) by 16 argmax rounds with remove-by-index. Also m and fill indices.
// Proven, unchanged.
// ---------------------------------------------------------------------------
__global__ __launch_bounds__(64) void merge_topk(
    const double* __restrict__ candV, const int* __restrict__ candI,
    const int* __restrict__ cnts, const int* __restrict__ sec,
    const int* __restrict__ act,
    int* __restrict__ top_idx, int* __restrict__ fill_idx,
    int* __restrict__ m_arr)
{
    int c = blockIdx.x;
    int lane = threadIdx.x;

    const double* cbV = candV + (size_t)c * NSL * TOPK;   // 128 entries
    const int* cbI = candI + (size_t)c * NSL * TOPK;
    double v0 = cbV[lane];
    int i0 = cbI[lane];
    double v1 = cbV[lane + 64];
    int i1 = cbI[lane + 64];

    for (int r = 0; r < TOPK; ++r) {
        double bv;
        int bi;
        if (better(v0, i0, v1, i1)) { bv = v0; bi = i0; }
        else                        { bv = v1; bi = i1; }
        for (int o = 32; o > 0; o >>= 1) {
            double ov = __shfl_xor(bv, o);
            int oi = __shfl_xor(bi, o);
            if (better(ov, oi, bv, bi)) { bv = ov; bi = oi; }
        }
        if (i0 == bi)      { v0 = -INFINITY; i0 = IDX_SENT; }
        else if (i1 == bi) { v1 = -INFINITY; i1 = IDX_SENT; }
        if (lane == 0) top_idx[c * TOPK + r] = (bi == IDX_SENT) ? -1 : bi;
    }

    // m = min(16, total active in sector)
    int cl = (lane < NSL) ? cnts[c * NSL + lane] : 0;
    for (int o = 32; o > 0; o >>= 1) cl += __shfl_xor(cl, o);
    if (lane == 0) m_arr[c] = (cl < TOPK) ? cl : TOPK;

    // fill indices: first 16 j failing the predicate (usually 1 iteration)
    int cnt2 = 0;
    for (int basej = 0; basej < N && cnt2 < TOPK; basej += 64) {
        int j = basej + lane;
        bool fail = !((act[j] != 0) && (sec[j] == c));
        unsigned long long mask = __ballot(fail);
        if (fail) {
            int rank = cnt2 + __popcll(mask & ((1ull << lane) - 1));
            if (rank < TOPK) fill_idx[c * TOPK + rank] = j;
        }
        cnt2 += __popcll(mask);
    }
}

// ---------------------------------------------------------------------------
// K4: write outputs (weight, index-as-float, valid-as-float planes).
// Proven, unchanged.
// ---------------------------------------------------------------------------
__global__ __launch_bounds__(NT) void write_out(const float* __restrict__ s1f,
                                                const double* __restrict__ s2g,
                                                const int* __restrict__ sec,
                                                const int* __restrict__ act,
                                                const int* __restrict__ top_idx,
                                                const int* __restrict__ fill_idx,
                                                const int* __restrict__ m_arr,
                                                float* __restrict__ out) {
    int gid = blockIdx.x * NT + threadIdx.x;  // N*TOPK total
    int i = gid >> 4;
    int slot = gid & 15;

    float wgt = 0.0f;
    float fidx;
    float fvalid = 0.0f;

    if (act[i] == 0) {
        fidx = (float)slot;  // all -inf row: stable top_k -> indices 0..15
    } else {
        int c = sec[i];
        int m = m_arr[c];
        if (slot < m) {
            int j = top_idx[c * TOPK + slot];
            double x = (double)s1f[i] + s2g[j];
            double attv = (x >= 0.0) ? x : NEG_SLOPE * x;
            wgt = (float)attv;
            fvalid = 1.0f;
            fidx = (float)j;
        } else {
            fidx = (float)fill_idx[c * TOPK + (slot - m)];
        }
    }

    out[gid] = wgt;
    out[N * TOPK + gid] = fidx;
    out[2 * N * TOPK + gid] = fvalid;
}

extern "C" void kernel_launch(void* const* d_in, const int* in_sizes, int n_in,
                              void* d_out, int out_size, void* d_ws, size_t ws_size,
                              hipStream_t stream) {
    const float* E = (const float*)d_in[0];
    const float* W = (const float*)d_in[1];
    const float* a = (const float*)d_in[2];
    const int* sec = (const int*)d_in[3];
    const int* act = (const int*)d_in[4];  // bool input uploaded as int32

    // workspace (~115 KB, 8-byte aligned first) — proven range
    char* ws = (char*)d_ws;
    double* s2g = (double*)ws;                     // N f64
    double* candV = s2g + N;                       // NSEC*NSL*TOPK = 1408 f64
    float* s1f = (float*)(candV + NSEC * NSL * TOPK);  // N f32
    int* candI = (int*)(s1f + N);                  // 1408 i32
    int* cnts = candI + NSEC * NSL * TOPK;         // NSEC*NSL = 88
    int* top_idx = cnts + NSEC * NSL;              // NSEC*TOPK
    int* fill_idx = top_idx + NSEC * TOPK;         // NSEC*TOPK
    int* m_arr = fill_idx + NSEC * TOPK;           // NSEC

    float* out = (float*)d_out;

    hipLaunchKernelGGL(compute_v_s, dim3(NB), dim3(NT), 0, stream,
                       E, W, a, s1f, s2g);
    hipLaunchKernelGGL(slice_topk, dim3(NSEC * NSL), dim3(NT), 0, stream,
                       s2g, sec, act, candV, candI, cnts);
    hipLaunchKernelGGL(merge_topk, dim3(NSEC), dim3(64), 0, stream,
                       candV, candI, cnts, sec, act, top_idx, fill_idx, m_arr);
    hipLaunchKernelGGL(write_out, dim3((N * TOPK) / NT), dim3(NT), 0, stream,
                       s1f, s2g, sec, act, top_idx, fill_idx, m_arr, out);
}